// Round 5
// baseline (88.095 us; speedup 1.0000x reference)
//
#include <hip/hip_runtime.h>
#include <hip/hip_fp16.h>
#include <math.h>

// B=8, C=64, H=W=64, O=128, K=3, N=9, stride=1, pad=1
// ws layout (7.36 MB total):
//   xTh  @ 0        : fp16 [8][4096][64]          = 4,194,304 B
//   WtH  @ 4194304  : fp16 [9][128][64]           =   147,456 B
//   recP @ 4341760  : uint2 [9][32768]            = 2,359,296 B
//   modH @ 6701056  : fp16 [9][32768]             =   589,824 B
//   wOrd @ 7290880  : f32  [576][28]              =    64,512 B

typedef _Float16 half8_t __attribute__((ext_vector_type(8)));
typedef float f32x4 __attribute__((ext_vector_type(4)));

// ---------------------------------------------------------------------------
// T1: x (B,C,H,W) f32 -> xTh (B, H*W, C) fp16
// ---------------------------------------------------------------------------
__global__ __launch_bounds__(256) void k_transpose_x(const float* __restrict__ x,
                                                     __half* __restrict__ xTh) {
    __shared__ float tile[64][65];
    int blk = blockIdx.x;
    int b = blk >> 6;
    int pt = blk & 63;
    int t = threadIdx.x;
    int lane = t & 63;
    int cq = t >> 6;
    const float* xb = x + ((size_t)b << 18);
#pragma unroll
    for (int r = 0; r < 16; ++r) {
        int c = cq * 16 + r;
        tile[c][lane] = xb[((size_t)c << 12) + pt * 64 + lane];
    }
    __syncthreads();
    int p = t >> 2, qc = t & 3;
    __align__(16) __half hv[16];
#pragma unroll
    for (int k = 0; k < 16; ++k) hv[k] = __float2half_rn(tile[qc * 16 + k][p]);
    __half* dst = xTh + ((size_t)b << 18) + (size_t)(pt * 64 + p) * 64 + qc * 16;
    ((uint4*)dst)[0] = ((uint4*)hv)[0];
    ((uint4*)dst)[1] = ((uint4*)hv)[1];
}

// ---------------------------------------------------------------------------
// Prep (fused): conv_w -> WtH (9,O,C) fp16 ; stage1 weights -> wOrd[(c*9+tap)*28+ch]
// ---------------------------------------------------------------------------
__global__ __launch_bounds__(256) void k_prep(const float* __restrict__ cw,
                                              const float* __restrict__ shift_w,
                                              const float* __restrict__ mod_w,
                                              __half* __restrict__ WtH,
                                              float* __restrict__ wOrd) {
    int t = blockIdx.x * 256 + threadIdx.x;
    if (t < 73728) {
        int c = t & 63;
        int o = (t >> 6) & 127;
        int n = t >> 13;
        WtH[t] = __float2half_rn(cw[(o * 64 + c) * 9 + n]);
    } else {
        int u = t - 73728;
        if (u < 16128) {
            int ch = u % 28;
            int r = u / 28;            // r = c*9 + tap
            int c = r / 9, tap = r % 9;
            float v = 0.f;
            if (ch < 18) v = shift_w[(ch * 64 + c) * 9 + tap];
            else if (ch < 27) v = mod_w[((ch - 18) * 64 + c) * 9 + tap];
            wOrd[u] = v;
        }
    }
}

// ---------------------------------------------------------------------------
// S1: 27-ch 3x3 conv (pad 1) + gather-record precompute.
//   grid 512 x 256; block = 64 pixels (2 rows x 32 cols) x 8 c-slices.
//   Thread = (slice s, col p): 2 pixels (row pair) x 8 channels -> each
//   wave-uniform ds_read_b128 of weights feeds 8 FMAs (VALU-bound, not
//   LDS-issue-bound like R2/R3, not latency-bound like R4).
//   Records: nonzero-weight slots sorted FIRST (k_main zero-skip).
// ---------------------------------------------------------------------------
__global__ __launch_bounds__(256, 2) void k_stage1(
    const float* __restrict__ x, const float* __restrict__ wOrd,
    const float* __restrict__ shift_b, const float* __restrict__ mod_b,
    uint2* __restrict__ recP, __half* __restrict__ modH) {
    __shared__ float wl[16128];   // 63 KB: weights, later reused as reduce buf
    int t = threadIdx.x;

#pragma unroll
    for (int i = 0; i < 16; ++i) {
        int idx = i * 256 + t;
        if (idx < 4032) ((f32x4*)wl)[idx] = ((const f32x4*)wOrd)[idx];
    }
    __syncthreads();

    int bk = blockIdx.x;
    int b = bk >> 6;
    int u = bk & 63;
    int rp = u >> 1, hf = u & 1;
    int s = t >> 5;                 // c-slice 0..7
    int p = t & 31;                 // col within half-row
    int i0 = rp * 2;
    int jj = hf * 32 + p;
    const float* xb = x + ((size_t)b << 18);

    float acc0[27], acc1[27];
#pragma unroll
    for (int ch = 0; ch < 27; ++ch) { acc0[ch] = 0.f; acc1[ch] = 0.f; }

    for (int cc = 0; cc < 8; ++cc) {
        int c = s * 8 + cc;
        const float* xc = xb + ((size_t)c << 12);
        float xr[4][3];
#pragma unroll
        for (int rr = 0; rr < 4; ++rr) {
            int row = i0 - 1 + rr;
            bool rok = (unsigned)row < 64u;
#pragma unroll
            for (int dc = 0; dc < 3; ++dc) {
                int col = jj - 1 + dc;
                bool ok = rok && ((unsigned)col < 64u);
                xr[rr][dc] = ok ? xc[row * 64 + col] : 0.f;
            }
        }
        int wbase = c * 252;
#pragma unroll
        for (int tr = 0; tr < 3; ++tr)
#pragma unroll
            for (int tc = 0; tc < 3; ++tc) {
                int wi = wbase + (tr * 3 + tc) * 28;
                float xa = xr[tr][tc], xv = xr[tr + 1][tc];
#pragma unroll
                for (int chg = 0; chg < 7; ++chg) {
                    f32x4 wv = *(const f32x4*)&wl[wi + chg * 4];
#pragma unroll
                    for (int e = 0; e < 4; ++e) {
                        int ch = chg * 4 + e;
                        if (ch < 27) {
                            acc0[ch] = fmaf(wv[e], xa, acc0[ch]);
                            acc1[ch] = fmaf(wv[e], xv, acc1[ch]);
                        }
                    }
                }
            }
    }
    __syncthreads();   // conv reads of wl done; reuse as reduce buffer

    // tree-reduce 8 slices -> slice 0, staying inside the 63 KB buffer
    if (s >= 4) {
#pragma unroll
        for (int ch = 0; ch < 27; ++ch) {
            wl[((s - 4) * 64 + p) * 27 + ch] = acc0[ch];
            wl[((s - 4) * 64 + 32 + p) * 27 + ch] = acc1[ch];
        }
    }
    __syncthreads();
    if (s < 4) {
#pragma unroll
        for (int ch = 0; ch < 27; ++ch) {
            acc0[ch] += wl[(s * 64 + p) * 27 + ch];
            acc1[ch] += wl[(s * 64 + 32 + p) * 27 + ch];
        }
    }
    __syncthreads();
    if (s >= 2 && s < 4) {
#pragma unroll
        for (int ch = 0; ch < 27; ++ch) {
            wl[((s - 2) * 64 + p) * 27 + ch] = acc0[ch];
            wl[((s - 2) * 64 + 32 + p) * 27 + ch] = acc1[ch];
        }
    }
    __syncthreads();
    if (s < 2) {
#pragma unroll
        for (int ch = 0; ch < 27; ++ch) {
            acc0[ch] += wl[(s * 64 + p) * 27 + ch];
            acc1[ch] += wl[(s * 64 + 32 + p) * 27 + ch];
        }
    }
    __syncthreads();
    if (s == 1) {
#pragma unroll
        for (int ch = 0; ch < 27; ++ch) {
            wl[p * 27 + ch] = acc0[ch];
            wl[(32 + p) * 27 + ch] = acc1[ch];
        }
    }
    __syncthreads();
    if (s == 0) {
#pragma unroll
        for (int ch = 0; ch < 27; ++ch) {
            acc0[ch] += wl[p * 27 + ch];
            acc1[ch] += wl[(32 + p) * 27 + ch];
            wl[p * 27 + ch] = acc0[ch];
            wl[(32 + p) * 27 + ch] = acc1[ch];
        }
    }
    __syncthreads();

    // tail: all 64 pixels x 9 n, spread over waves 0..2 (3 n's each)
    int pl = t & 63;
    int wg = t >> 6;
    if (wg < 3) {
        float sv[27];
#pragma unroll
        for (int ch = 0; ch < 27; ++ch) sv[ch] = wl[pl * 27 + ch];
        int ii = i0 + (pl >> 5);
        int jt = hf * 32 + (pl & 31);
        int pix = (b << 12) + ii * 64 + jt;
#pragma unroll
        for (int k = 0; k < 3; ++k) {
            int n = wg * 3 + k;
            float px = ((sv[n] + shift_b[n]) + (float)(n / 3 - 1)) + (float)(ii + 1);
            float py = ((sv[9 + n] + shift_b[9 + n]) + (float)(n % 3 - 1)) + (float)(jt + 1);
            float mz = sv[18 + n] + mod_b[n];
            float mod = 1.f / (1.f + expf(-mz));

            float fx = floorf(px), fy = floorf(py);
            int ltx = (int)fminf(fmaxf(fx, 0.f), 63.f);
            int lty = (int)fminf(fmaxf(fy, 0.f), 63.f);
            int rbx = (int)fminf(fmaxf(fx + 1.f, 0.f), 63.f);
            int rby = (int)fminf(fmaxf(fy + 1.f, 0.f), 63.f);
            int pxi = (int)fminf(fmaxf(px, 0.f), 63.f);
            int pyi = (int)fminf(fmaxf(py, 0.f), 63.f);

            int g_lt = (1 + ltx - pxi) * (1 + lty - pyi);
            int g_rb = (1 - rbx + pxi) * (1 - rby + pyi);
            int g_lb = (1 + ltx - pxi) * (1 + rby - pyi);
            int g_rt = (1 - rbx + pxi) * (1 - lty + pyi);

            // per-slot (idx, g) with pad-invalid slots zeroed
            unsigned si0, si1, si2, si3;
            int g0, g1, g2, g3;
            {
                bool v0 = (ltx >= 1) && (lty >= 1);
                bool v1 = (rbx >= 1) && (rby >= 1);
                bool v2 = (ltx >= 1) && (rby >= 1);
                bool v3 = (rbx >= 1) && (lty >= 1);
                si0 = v0 ? (unsigned)((ltx - 1) * 64 + (lty - 1)) : 0u;
                si1 = v1 ? (unsigned)((rbx - 1) * 64 + (rby - 1)) : 0u;
                si2 = v2 ? (unsigned)((ltx - 1) * 64 + (rby - 1)) : 0u;
                si3 = v3 ? (unsigned)((rbx - 1) * 64 + (lty - 1)) : 0u;
                g0 = v0 ? g_lt : 0;
                g1 = v1 ? g_rb : 0;
                g2 = v2 ? g_lb : 0;
                g3 = v3 ? g_rt : 0;
            }
            // sorting network: nonzero-g slots first (branchless cndmask swaps)
#define CSW(ga, gb, ia, ib)                                   \
    {                                                          \
        bool sw = (ga == 0) && (gb != 0);                      \
        int tg = ga; unsigned ti = ia;                         \
        ga = sw ? gb : ga;  ia = sw ? ib : ia;                 \
        gb = sw ? tg : gb;  ib = sw ? ti : ib;                 \
    }
            CSW(g0, g1, si0, si1);
            CSW(g2, g3, si2, si3);
            CSW(g0, g2, si0, si2);
            CSW(g1, g3, si1, si3);
            CSW(g1, g2, si1, si2);
#undef CSW
            unsigned w0 = si0 | (si1 << 12) | ((unsigned)g0 << 24) |
                          ((unsigned)g1 << 26) | ((unsigned)g2 << 28) |
                          ((unsigned)g3 << 30);
            unsigned w1 = si2 | (si3 << 12);
            recP[n * 32768 + pix] = make_uint2(w0, w1);
            modH[n * 32768 + pix] = __float2half_rn(mod);
        }
    }
}

// ---------------------------------------------------------------------------
// k_main helpers
// ---------------------------------------------------------------------------
__device__ __forceinline__ void gather_slot(__half2* a, const __half* xb, int cg,
                                            unsigned rcx, int j, int id, float mod) {
    float wf = (float)((rcx >> (24 + 2 * j)) & 3) * mod;
    __half2 wh = __half2(__float2half_rn(wf), __float2half_rn(wf));
    uint4 v = *(const uint4*)(xb + (id << 6) + (cg << 3));
    const __half2* vv = (const __half2*)&v;
    a[0] = __hfma2(wh, vv[0], a[0]);
    a[1] = __hfma2(wh, vv[1], a[1]);
    a[2] = __hfma2(wh, vv[2], a[2]);
    a[3] = __hfma2(wh, vv[3], a[3]);
}

__device__ __forceinline__ void build_tile(const uint2* __restrict__ recN,
                                           const __half* __restrict__ modN,
                                           const __half* __restrict__ xb,
                                           unsigned char* __restrict__ buf, int t) {
#pragma unroll
    for (int r = 0; r < 2; ++r) {
        int task = r * 256 + t;
        int m = task >> 3;
        int cg = task & 7;
        uint2 rc = recN[m];
        float mod = __half2float(modN[m]);
        int id0 = (int)(rc.x & 0xFFF), id1 = (int)((rc.x >> 12) & 0xFFF);
        int id2 = (int)(rc.y & 0xFFF), id3 = (int)((rc.y >> 12) & 0xFFF);
        __align__(16) __half2 a[4];
        a[0] = __half2(0, 0); a[1] = __half2(0, 0);
        a[2] = __half2(0, 0); a[3] = __half2(0, 0);
        gather_slot(a, xb, cg, rc.x, 0, id0, mod);
        gather_slot(a, xb, cg, rc.x, 1, id1, mod);
        unsigned g23 = rc.x >> 28;      // slots 2,3 weight bits
        if (__any((int)g23)) {           // usually false (interior: 2 nonzero)
            gather_slot(a, xb, cg, rc.x, 2, id2, mod);
            gather_slot(a, xb, cg, rc.x, 3, id3, mod);
        }
        *(uint4*)&buf[(m << 7) | ((cg ^ (m & 7)) << 4)] = *(uint4*)a;
    }
}

// ---------------------------------------------------------------------------
// Main MFMA GEMM: out[pix][o] = sum_n sum_c A_n[pix][c] * W_n[c][o]
//   grid 512 x 256 (4 waves: wm (M), wn (N)); tile 64 pix x 128 o
//   A: fp16 LDS [64][64] swizzled, TRIPLE-buffered -> ONE barrier per n;
//   next-n gathers issue during current-n MFMA (cross-phase overlap).
// ---------------------------------------------------------------------------
__global__ __launch_bounds__(256, 2) void k_main(
    const __half* __restrict__ xTh, const __half* __restrict__ WtH,
    const uint2* __restrict__ recP, const __half* __restrict__ modH,
    float* __restrict__ out) {
    __shared__ __align__(16) unsigned char AlB[3 * 8192];   // 3 A slabs; Ep aliases slab 0
    float* Ep = (float*)AlB;

    int t = threadIdx.x;
    int l = t & 63;
    int w = t >> 6;
    int wm = w >> 1, wn = w & 1;
    int pix0 = blockIdx.x * 64;
    int b = pix0 >> 12;
    int pbase = pix0 & 4095;
    const __half* xb = xTh + ((size_t)b << 18);
    int l15 = l & 15, lhi = l >> 4;

    f32x4 acc[2][4];
#pragma unroll
    for (int f = 0; f < 2; ++f)
#pragma unroll
        for (int g = 0; g < 4; ++g) acc[f][g] = (f32x4){0.f, 0.f, 0.f, 0.f};

    // prologue: build n=0 into slab 0
    build_tile(recP + pix0, modH + pix0, xb, AlB, t);

#pragma unroll
    for (int n = 0; n < 9; ++n) {
        // B fragments for current n (global; consumed after the barrier)
        const __half* Wn = WtH + n * 8192;
        uint4 Bv[2][4];
#pragma unroll
        for (int ks = 0; ks < 2; ++ks)
#pragma unroll
            for (int g = 0; g < 4; ++g)
                Bv[ks][g] = *(const uint4*)(Wn + ((wn * 64 + g * 16 + l15) << 6) +
                                            ks * 32 + (lhi << 3));

        // build next n's A tile into the next slab (overlaps this n's MFMA
        // across the single barrier via VMEM-in-flight)
        if (n < 8)
            build_tile(recP + (n + 1) * 32768 + pix0, modH + (n + 1) * 32768 + pix0,
                       xb, AlB + 8192 * ((n + 1) % 3), t);

        __syncthreads();

        const unsigned char* bufc = AlB + 8192 * (n % 3);
#pragma unroll
        for (int ks = 0; ks < 2; ++ks) {
            half8_t Af[2];
#pragma unroll
            for (int f = 0; f < 2; ++f) {
                int row = wm * 32 + f * 16 + l15;
                int gr = (ks * 4 + lhi) ^ (row & 7);
                Af[f] = *(const half8_t*)&bufc[(row << 7) | (gr << 4)];
            }
#pragma unroll
            for (int f = 0; f < 2; ++f)
#pragma unroll
                for (int g = 0; g < 4; ++g) {
                    half8_t Bf = *(half8_t*)&Bv[ks][g];
                    acc[f][g] = __builtin_amdgcn_mfma_f32_16x16x32_f16(
                        Af[f], Bf, acc[f][g], 0, 0, 0);
                }
        }
    }

    // Epilogue via LDS: 4 rounds of 32 o-rows -> coalesced float4 stores
    float* ob = out + ((size_t)b << 19);
#pragma unroll
    for (int r = 0; r < 4; ++r) {
        if (wn == (r >> 1)) {
#pragma unroll
            for (int f = 0; f < 2; ++f)
#pragma unroll
                for (int gg = 0; gg < 2; ++gg) {
                    int g = (r & 1) * 2 + gg;
                    int o_loc = gg * 16 + l15;
                    int m4 = wm * 8 + f * 4 + lhi;
                    int gr = m4 ^ (o_loc & 7);
                    *(f32x4*)&Ep[(o_loc << 6) + (gr << 2)] = acc[f][g];
                }
        }
        __syncthreads();
        {
            int o_loc = t >> 3;
            int mseg = t & 7;
            int g1 = mseg ^ (o_loc & 7);
            int g2 = (8 + mseg) ^ (o_loc & 7);
            float4 fa = *(float4*)&Ep[(o_loc << 6) + (g1 << 2)];
            float4 fb = *(float4*)&Ep[(o_loc << 6) + (g2 << 2)];
            float* dst = ob + ((size_t)(r * 32 + o_loc) << 12) + pbase;
            *(float4*)(dst + mseg * 4) = fa;
            *(float4*)(dst + 32 + mseg * 4) = fb;
        }
        __syncthreads();
    }
}

// ---------------------------------------------------------------------------
extern "C" void kernel_launch(void* const* d_in, const int* in_sizes, int n_in,
                              void* d_out, int out_size, void* d_ws, size_t ws_size,
                              hipStream_t stream) {
    const float* x = (const float*)d_in[0];
    const float* shift_w = (const float*)d_in[1];
    const float* shift_b = (const float*)d_in[2];
    const float* mod_w = (const float*)d_in[3];
    const float* mod_b = (const float*)d_in[4];
    const float* conv_w = (const float*)d_in[5];
    float* out = (float*)d_out;

    char* ws = (char*)d_ws;
    __half* xTh = (__half*)ws;                       // 4 MB
    __half* WtH = (__half*)(ws + 4194304);           // 144 KB
    uint2* recP = (uint2*)(ws + 4341760);            // 2.25 MB
    __half* modH = (__half*)(ws + 6701056);          // 576 KB
    float* wOrd = (float*)(ws + 7290880);            // 63 KB   (total 7.36 MB)

    k_transpose_x<<<dim3(512), dim3(256), 0, stream>>>(x, xTh);
    k_prep<<<dim3(352), dim3(256), 0, stream>>>(conv_w, shift_w, mod_w, WtH, wOrd);
    k_stage1<<<dim3(512), dim3(256), 0, stream>>>(x, wOrd, shift_b, mod_b,
                                                  recP, modH);
    k_main<<<dim3(512), dim3(256), 0, stream>>>(xTh, WtH, recP, modH, out);
}

// Round 6
// 69.796 us; speedup vs baseline: 1.2622x; 1.2622x over previous
//
#include <hip/hip_runtime.h>
#include <hip/hip_fp16.h>
#include <math.h>

// B=8, C=64, H=W=64, O=128, K=3, N=9, stride=1, pad=1
// ws layout (7.03 MB total):
//   xTh  @ 0        : fp16 [8][4096 pix][64 c]    = 4,194,304 B
//   WtH  @ 4194304  : fp16 [9][128 o][64 c]       =   147,456 B
//   WtSh @ 4341760  : fp16 [9][32 ch][64 c]       =    36,864 B
//   WtSl @ 4378624  : fp16 [9][32 ch][64 c]       =    36,864 B
//   recP @ 4415488  : uint2 [9][32768]            = 2,359,296 B
//   modH @ 6774784  : fp16 [9][32768]             =   589,824 B

typedef _Float16 half8_t __attribute__((ext_vector_type(8)));
typedef float f32x4 __attribute__((ext_vector_type(4)));

// ---------------------------------------------------------------------------
// T1: x (B,C,H,W) f32 -> xTh (B, H*W, C) fp16
// ---------------------------------------------------------------------------
__global__ __launch_bounds__(256) void k_transpose_x(const float* __restrict__ x,
                                                     __half* __restrict__ xTh) {
    __shared__ float tile[64][65];
    int blk = blockIdx.x;
    int b = blk >> 6;
    int pt = blk & 63;
    int t = threadIdx.x;
    int lane = t & 63;
    int cq = t >> 6;
    const float* xb = x + ((size_t)b << 18);
#pragma unroll
    for (int r = 0; r < 16; ++r) {
        int c = cq * 16 + r;
        tile[c][lane] = xb[((size_t)c << 12) + pt * 64 + lane];
    }
    __syncthreads();
    int p = t >> 2, qc = t & 3;
    __align__(16) __half hv[16];
#pragma unroll
    for (int k = 0; k < 16; ++k) hv[k] = __float2half_rn(tile[qc * 16 + k][p]);
    __half* dst = xTh + ((size_t)b << 18) + (size_t)(pt * 64 + p) * 64 + qc * 16;
    ((uint4*)dst)[0] = ((uint4*)hv)[0];
    ((uint4*)dst)[1] = ((uint4*)hv)[1];
}

// ---------------------------------------------------------------------------
// Prep: conv_w -> WtH (9,O,C) fp16 ; stage1 weights -> WtSh/WtSl (9,32ch,64c)
//   split precision: w = Wh + Wl (each fp16) so stage1 GEMM carries ~22
//   mantissa bits -> no floor()-flips vs the fp32 reference path.
// ---------------------------------------------------------------------------
__global__ __launch_bounds__(256) void k_prep(const float* __restrict__ cw,
                                              const float* __restrict__ shift_w,
                                              const float* __restrict__ mod_w,
                                              __half* __restrict__ WtH,
                                              __half* __restrict__ WtSh,
                                              __half* __restrict__ WtSl) {
    int t = blockIdx.x * 256 + threadIdx.x;
    if (t < 73728) {
        int c = t & 63;
        int o = (t >> 6) & 127;
        int n = t >> 13;
        WtH[t] = __float2half_rn(cw[(o * 64 + c) * 9 + n]);
    } else {
        int u = t - 73728;
        if (u < 18432) {
            int c = u & 63;
            int ch = (u >> 6) & 31;
            int tap = u >> 11;
            float w = 0.f;
            if (ch < 18) w = shift_w[(ch * 64 + c) * 9 + tap];
            else if (ch < 27) w = mod_w[((ch - 18) * 64 + c) * 9 + tap];
            _Float16 h = (_Float16)w;
            _Float16 lo = (_Float16)(w - (float)h);
            WtSh[u] = *(__half*)&h;
            WtSl[u] = *(__half*)&lo;
        }
    }
}

// ---------------------------------------------------------------------------
// S1 (MFMA): 27-ch 3x3 conv as 9 tap-shifted GEMMs + record precompute.
//   grid 512 (b*64+row) x 256 threads; wave = 16 pixels (cols w*16..+15),
//   C-tile per wave = 16 pix x 32 ch, K = 9 taps x 64 c.
//   A-frags: f32 x loaded direct (64B-coalesced), split to fp16 hi+lo in-reg.
//   acc += Ah*Bh + Ah*Bl + Al*Bh  (err ~ term*2^-22, no floor flips).
//   Epilogue: C -> LDS -> offset/record math (R4 format), fused.
// ---------------------------------------------------------------------------
__global__ __launch_bounds__(256, 2) void k_stage1g(
    const float* __restrict__ x, const __half* __restrict__ WtSh,
    const __half* __restrict__ WtSl, const float* __restrict__ shift_b,
    const float* __restrict__ mod_b, uint2* __restrict__ recP,
    __half* __restrict__ modH) {
    __shared__ float Cl[4][16][33];
    int t = threadIdx.x;
    int l = t & 63;
    int w = t >> 6;
    int l15 = l & 15, lhi = l >> 4;
    int bk = blockIdx.x;
    int b = bk >> 6;
    int row = bk & 63;
    const float* xb = x + ((size_t)b << 18);

    f32x4 acc[2];
    acc[0] = (f32x4){0.f, 0.f, 0.f, 0.f};
    acc[1] = (f32x4){0.f, 0.f, 0.f, 0.f};

    int colp = w * 16 + l15;          // this lane's pixel column

#pragma unroll
    for (int tr = 0; tr < 3; ++tr) {
        int rsh = row + tr - 1;
        if ((unsigned)rsh >= 64u) continue;   // wave-uniform skip (border rows)
#pragma unroll
        for (int tc = 0; tc < 3; ++tc) {
            int tap = tr * 3 + tc;
            int cs = colp + tc - 1;
            bool vcol = (unsigned)cs < 64u;
            int csc = vcol ? cs : 0;
            const float* xr = xb + rsh * 64 + csc;
            const __half* bh0 = WtSh + tap * 2048 + l15 * 64 + (lhi << 3);
            const __half* bl0 = WtSl + tap * 2048 + l15 * 64 + (lhi << 3);
#pragma unroll
            for (int chf = 0; chf < 2; ++chf) {
                float v[8];
#pragma unroll
                for (int e = 0; e < 8; ++e)
                    v[e] = xr[(chf * 32 + (lhi << 3) + e) << 12];
                half8_t Ah, Al;
#pragma unroll
                for (int e = 0; e < 8; ++e) {
                    float vv = vcol ? v[e] : 0.f;
                    _Float16 h = (_Float16)vv;
                    Ah[e] = h;
                    Al[e] = (_Float16)(vv - (float)h);
                }
#pragma unroll
                for (int nf = 0; nf < 2; ++nf) {
                    half8_t Bh = *(const half8_t*)(bh0 + chf * 32 + nf * 1024);
                    half8_t Bl = *(const half8_t*)(bl0 + chf * 32 + nf * 1024);
                    acc[nf] = __builtin_amdgcn_mfma_f32_16x16x32_f16(
                        Ah, Bh, acc[nf], 0, 0, 0);
                    acc[nf] = __builtin_amdgcn_mfma_f32_16x16x32_f16(
                        Ah, Bl, acc[nf], 0, 0, 0);
                    acc[nf] = __builtin_amdgcn_mfma_f32_16x16x32_f16(
                        Al, Bh, acc[nf], 0, 0, 0);
                }
            }
        }
    }

    // C -> LDS: lane holds 4 pixel-rows x 1 ch per n-frag
#pragma unroll
    for (int nf = 0; nf < 2; ++nf)
#pragma unroll
        for (int v4 = 0; v4 < 4; ++v4)
            Cl[w][(lhi << 2) + v4][nf * 16 + l15] = acc[nf][v4];
    __syncthreads();

    // records: 576 tasks (64 pix x 9 n) over 256 threads
#pragma unroll
    for (int j = 0; j < 3; ++j) {
        int rid = j * 256 + t;
        if (rid < 576) {
            int pb = rid & 63;
            int n = rid >> 6;
            float sx = Cl[pb >> 4][pb & 15][n];
            float sy = Cl[pb >> 4][pb & 15][9 + n];
            float sm = Cl[pb >> 4][pb & 15][18 + n];

            float px = ((sx + shift_b[n]) + (float)(n / 3 - 1)) + (float)(row + 1);
            float py = ((sy + shift_b[9 + n]) + (float)(n % 3 - 1)) + (float)(pb + 1);
            float mod = 1.f / (1.f + expf(-(sm + mod_b[n])));

            float fx = floorf(px), fy = floorf(py);
            int ltx = (int)fminf(fmaxf(fx, 0.f), 63.f);
            int lty = (int)fminf(fmaxf(fy, 0.f), 63.f);
            int rbx = (int)fminf(fmaxf(fx + 1.f, 0.f), 63.f);
            int rby = (int)fminf(fmaxf(fy + 1.f, 0.f), 63.f);
            int pxi = (int)fminf(fmaxf(px, 0.f), 63.f);
            int pyi = (int)fminf(fmaxf(py, 0.f), 63.f);

            int g_lt = (1 + ltx - pxi) * (1 + lty - pyi);
            int g_rb = (1 - rbx + pxi) * (1 - rby + pyi);
            int g_lb = (1 + ltx - pxi) * (1 + rby - pyi);
            int g_rt = (1 - rbx + pxi) * (1 - lty + pyi);

            int qxa[4] = {ltx, rbx, ltx, rbx};
            int qya[4] = {lty, rby, rby, lty};
            int gga[4] = {g_lt, g_rb, g_lb, g_rt};
            unsigned w0 = 0, w1 = 0;
#pragma unroll
            for (int jj = 0; jj < 4; ++jj) {
                bool valid = (qxa[jj] >= 1) && (qya[jj] >= 1);
                unsigned idx = valid ? (unsigned)((qxa[jj] - 1) * 64 + (qya[jj] - 1)) : 0u;
                unsigned gc = valid ? (unsigned)gga[jj] : 0u;   // 0..2
                if (jj < 2) w0 |= idx << (12 * jj); else w1 |= idx << (12 * (jj - 2));
                w0 |= gc << (24 + 2 * jj);
            }
            int pix = (b << 12) + row * 64 + pb;
            recP[n * 32768 + pix] = make_uint2(w0, w1);
            modH[n * 32768 + pix] = __float2half_rn(mod);
        }
    }
}

// ---------------------------------------------------------------------------
// Main MFMA GEMM (R4-proven version): out[pix][o] = sum_n sum_c A_n[pix][c]*W_n[c][o]
//   grid 512 x 256 (4 waves); tile 64 pix x 128 o; wave-tile 32x64
//   A: fp16 LDS [64][64] XOR-swizzled; B: direct from global (L2-resident)
// ---------------------------------------------------------------------------
__global__ __launch_bounds__(256, 2) void k_main(
    const __half* __restrict__ xTh, const __half* __restrict__ WtH,
    const uint2* __restrict__ recP, const __half* __restrict__ modH,
    float* __restrict__ out) {
    __shared__ __align__(16) unsigned char AlB[8192];   // A tile fp16 [64][64] swizzled
    __shared__ __align__(16) float Ep[2048];            // epilogue 32 o x 64 m

    int t = threadIdx.x;
    int l = t & 63;
    int w = t >> 6;
    int wm = w >> 1, wn = w & 1;
    int pix0 = blockIdx.x * 64;
    int b = pix0 >> 12;
    int pbase = pix0 & 4095;
    const __half* xb = xTh + ((size_t)b << 18);
    int l15 = l & 15, lhi = l >> 4;

    f32x4 acc[2][4];
#pragma unroll
    for (int f = 0; f < 2; ++f)
#pragma unroll
        for (int g = 0; g < 4; ++g) acc[f][g] = (f32x4){0.f, 0.f, 0.f, 0.f};

    for (int n = 0; n < 9; ++n) {
        // B fragments direct from global: o = wn*64 + g*16 + l15, c = ks*32 + lhi*8
        const __half* Wn = WtH + n * 8192;
        uint4 Bv[2][4];
#pragma unroll
        for (int ks = 0; ks < 2; ++ks)
#pragma unroll
            for (int g = 0; g < 4; ++g)
                Bv[ks][g] = *(const uint4*)(Wn + ((wn * 64 + g * 16 + l15) << 6) +
                                            ks * 32 + (lhi << 3));

        // A build: 512 tasks (64 m x 8 cg), 2 per thread
        const uint2* recN = recP + n * 32768 + pix0;
        const __half* modN = modH + n * 32768 + pix0;
#pragma unroll
        for (int r = 0; r < 2; ++r) {
            int task = r * 256 + t;
            int m = task >> 3;
            int cg = task & 7;
            uint2 rc = recN[m];
            float mod = __half2float(modN[m]);
            int id[4] = {(int)(rc.x & 0xFFF), (int)((rc.x >> 12) & 0xFFF),
                         (int)(rc.y & 0xFFF), (int)((rc.y >> 12) & 0xFFF)};
            __align__(16) __half2 a[4];
            a[0] = __half2(0, 0); a[1] = __half2(0, 0);
            a[2] = __half2(0, 0); a[3] = __half2(0, 0);
#pragma unroll
            for (int j = 0; j < 4; ++j) {
                float wf = (float)((rc.x >> (24 + 2 * j)) & 3) * mod;
                __half2 wh = __half2(__float2half_rn(wf), __float2half_rn(wf));
                uint4 v = *(const uint4*)(xb + (id[j] << 6) + (cg << 3));
                const __half2* vv = (const __half2*)&v;
                a[0] = __hfma2(wh, vv[0], a[0]);
                a[1] = __hfma2(wh, vv[1], a[1]);
                a[2] = __hfma2(wh, vv[2], a[2]);
                a[3] = __hfma2(wh, vv[3], a[3]);
            }
            *(uint4*)&AlB[(m << 7) | ((cg ^ (m & 7)) << 4)] = *(uint4*)a;
        }
        __syncthreads();

        // MFMA: A rows wm*32 + f*16 + l15, k = ks*32 + lhi*8
#pragma unroll
        for (int ks = 0; ks < 2; ++ks) {
            half8_t Af[2];
#pragma unroll
            for (int f = 0; f < 2; ++f) {
                int row = wm * 32 + f * 16 + l15;
                int gr = (ks * 4 + lhi) ^ (row & 7);
                Af[f] = *(const half8_t*)&AlB[(row << 7) | (gr << 4)];
            }
#pragma unroll
            for (int f = 0; f < 2; ++f)
#pragma unroll
                for (int g = 0; g < 4; ++g) {
                    half8_t Bf = *(half8_t*)&Bv[ks][g];
                    acc[f][g] = __builtin_amdgcn_mfma_f32_16x16x32_f16(
                        Af[f], Bf, acc[f][g], 0, 0, 0);
                }
        }
        __syncthreads();
    }

    // Epilogue via LDS: 4 rounds of 32 o-rows -> coalesced float4 stores
    float* ob = out + ((size_t)b << 19);
#pragma unroll
    for (int r = 0; r < 4; ++r) {
        if (wn == (r >> 1)) {
#pragma unroll
            for (int f = 0; f < 2; ++f)
#pragma unroll
                for (int gg = 0; gg < 2; ++gg) {
                    int g = (r & 1) * 2 + gg;
                    int o_loc = gg * 16 + l15;
                    int m4 = wm * 8 + f * 4 + lhi;
                    int gr = m4 ^ (o_loc & 7);
                    *(f32x4*)&Ep[(o_loc << 6) + (gr << 2)] = acc[f][g];
                }
        }
        __syncthreads();
        {
            int o_loc = t >> 3;
            int mseg = t & 7;
            int g1 = mseg ^ (o_loc & 7);
            int g2 = (8 + mseg) ^ (o_loc & 7);
            float4 fa = *(float4*)&Ep[(o_loc << 6) + (g1 << 2)];
            float4 fb = *(float4*)&Ep[(o_loc << 6) + (g2 << 2)];
            float* dst = ob + ((size_t)(r * 32 + o_loc) << 12) + pbase;
            *(float4*)(dst + mseg * 4) = fa;
            *(float4*)(dst + 32 + mseg * 4) = fb;
        }
        __syncthreads();
    }
}

// ---------------------------------------------------------------------------
extern "C" void kernel_launch(void* const* d_in, const int* in_sizes, int n_in,
                              void* d_out, int out_size, void* d_ws, size_t ws_size,
                              hipStream_t stream) {
    const float* x = (const float*)d_in[0];
    const float* shift_w = (const float*)d_in[1];
    const float* shift_b = (const float*)d_in[2];
    const float* mod_w = (const float*)d_in[3];
    const float* mod_b = (const float*)d_in[4];
    const float* conv_w = (const float*)d_in[5];
    float* out = (float*)d_out;

    char* ws = (char*)d_ws;
    __half* xTh = (__half*)ws;                       // 4 MB
    __half* WtH = (__half*)(ws + 4194304);           // 144 KB
    __half* WtSh = (__half*)(ws + 4341760);          // 36 KB
    __half* WtSl = (__half*)(ws + 4378624);          // 36 KB
    uint2* recP = (uint2*)(ws + 4415488);            // 2.25 MB
    __half* modH = (__half*)(ws + 6774784);          // 576 KB  (total 7.03 MB)

    k_transpose_x<<<dim3(512), dim3(256), 0, stream>>>(x, xTh);
    k_prep<<<dim3(360), dim3(256), 0, stream>>>(conv_w, shift_w, mod_w,
                                                WtH, WtSh, WtSl);
    k_stage1g<<<dim3(512), dim3(256), 0, stream>>>(x, WtSh, WtSl, shift_b,
                                                   mod_b, recP, modH);
    k_main<<<dim3(512), dim3(256), 0, stream>>>(xTh, WtH, recP, modH, out);
}

// Round 7
// 68.942 us; speedup vs baseline: 1.2778x; 1.0124x over previous
//
#include <hip/hip_runtime.h>
#include <hip/hip_fp16.h>
#include <math.h>

// B=8, C=64, H=W=64, O=128, K=3, N=9, stride=1, pad=1
// ws layout (4.41 MB):
//   xTh  @ 0        : fp16 [8][4096 pix][64 c] = 4,194,304 B
//   WtH  @ 4194304  : fp16 [9][128 o][64 c]    =   147,456 B
//   WtSh @ 4341760  : fp16 [9][32 ch][64 c]    =    36,864 B
//   WtSl @ 4378624  : fp16 [9][32 ch][64 c]    =    36,864 B

typedef _Float16 half8_t __attribute__((ext_vector_type(8)));
typedef float f32x4 __attribute__((ext_vector_type(4)));

// ---------------------------------------------------------------------------
// k_pre: blocks 0..511  : x (B,C,H,W) f32 -> xTh (B,HW,C) fp16
//        blocks 512..871: conv_w -> WtH ; shift/mod weights -> WtSh/WtSl (split fp16)
// ---------------------------------------------------------------------------
__global__ __launch_bounds__(256) void k_pre(const float* __restrict__ x,
                                             const float* __restrict__ cw,
                                             const float* __restrict__ shift_w,
                                             const float* __restrict__ mod_w,
                                             __half* __restrict__ xTh,
                                             __half* __restrict__ WtH,
                                             __half* __restrict__ WtSh,
                                             __half* __restrict__ WtSl) {
    __shared__ float tile[64][65];
    int bid = blockIdx.x;
    int t = threadIdx.x;
    if (bid < 512) {
        int b = bid >> 6, pt = bid & 63;
        int lane = t & 63, cq = t >> 6;
        const float* xb = x + ((size_t)b << 18);
#pragma unroll
        for (int r = 0; r < 16; ++r) {
            int c = cq * 16 + r;
            tile[c][lane] = xb[((size_t)c << 12) + pt * 64 + lane];
        }
        __syncthreads();
        int p = t >> 2, qc = t & 3;
        __align__(16) __half hv[16];
#pragma unroll
        for (int k = 0; k < 16; ++k) hv[k] = __float2half_rn(tile[qc * 16 + k][p]);
        __half* dst = xTh + ((size_t)b << 18) + (size_t)(pt * 64 + p) * 64 + qc * 16;
        ((uint4*)dst)[0] = ((uint4*)hv)[0];
        ((uint4*)dst)[1] = ((uint4*)hv)[1];
    } else {
        int u = (bid - 512) * 256 + t;
        if (u < 73728) {
            int c = u & 63;
            int o = (u >> 6) & 127;
            int n = u >> 13;
            WtH[u] = __float2half_rn(cw[(o * 64 + c) * 9 + n]);
        } else {
            int v = u - 73728;
            if (v < 18432) {
                int c = v & 63;
                int ch = (v >> 6) & 31;
                int tap = v >> 11;
                float w = 0.f;
                if (ch < 18) w = shift_w[(ch * 64 + c) * 9 + tap];
                else if (ch < 27) w = mod_w[((ch - 18) * 64 + c) * 9 + tap];
                _Float16 h = (_Float16)w;
                _Float16 lo = (_Float16)(w - (float)h);
                WtSh[v] = *(__half*)&h;
                WtSl[v] = *(__half*)&lo;
            }
        }
    }
}

// ---------------------------------------------------------------------------
// k_fused: per block = 32 pixels (half image row) x all 128 outputs.
//   grid 1024 x 256 thr (4 waves) -> 4 blocks/CU, 16 waves/CU.
//   Phase A: stage1 27-ch conv via split-fp16 MFMA (wave = 16 pix x K-half),
//            LDS reduce, records (idx/weight/mod) -> LDS only.
//   Phase B: 9 x {A-gather-build -> 1 barrier -> MFMA}, A double-buffered.
//   Epilogue: LDS transpose (stride-33, scalar) -> coalesced float4 stores.
// ---------------------------------------------------------------------------
__global__ __launch_bounds__(256, 4) void k_fused(
    const float* __restrict__ x, const __half* __restrict__ xTh,
    const __half* __restrict__ WtH, const __half* __restrict__ WtSh,
    const __half* __restrict__ WtSl, const float* __restrict__ shift_b,
    const float* __restrict__ mod_b, float* __restrict__ out) {
    // arena: phase A: Cred f32[4][16][33] @0 (8448 B)
    //        phase B: A slabs fp16[32][64] @0 and @4096 ; Ep f32[32*33] @8448
    __shared__ __align__(16) unsigned char arena[12800];
    __shared__ uint2 recU[9][32];
    __shared__ float recF[9][32];

    int t = threadIdx.x;
    int l = t & 63;
    int w = t >> 6;
    int l15 = l & 15, lhi = l >> 4;

    int bk = blockIdx.x;
    int b = bk >> 7;
    int u = bk & 127;
    int row = u >> 1;
    int hf = u & 1;
    int col0 = hf * 32;

    const float* xb = x + ((size_t)b << 18);

    // ---------------- Phase A: stage1 conv (MFMA, split fp16) ----------------
    {
        int wp = w >> 1;                 // pixel 16-group (0,1)
        int wh = w & 1;                  // K-half (c 0..31 / 32..63)
        int colp = col0 + wp * 16 + l15;

        f32x4 accA[2];
        accA[0] = (f32x4){0.f, 0.f, 0.f, 0.f};
        accA[1] = (f32x4){0.f, 0.f, 0.f, 0.f};

#pragma unroll
        for (int tr = 0; tr < 3; ++tr) {
            int rsh = row + tr - 1;
            if ((unsigned)rsh >= 64u) continue;    // wave-uniform border skip
#pragma unroll
            for (int tc = 0; tc < 3; ++tc) {
                int tap = tr * 3 + tc;
                int cs = colp + tc - 1;
                bool vcol = (unsigned)cs < 64u;
                const float* xr = xb + rsh * 64 + (vcol ? cs : 0);
                float v[8];
#pragma unroll
                for (int e = 0; e < 8; ++e)
                    v[e] = xr[(wh * 32 + (lhi << 3) + e) << 12];
                half8_t Ah, Al;
#pragma unroll
                for (int e = 0; e < 8; ++e) {
                    float vv = vcol ? v[e] : 0.f;
                    _Float16 h = (_Float16)vv;
                    Ah[e] = h;
                    Al[e] = (_Float16)(vv - (float)h);
                }
                const __half* bh0 = WtSh + tap * 2048 + l15 * 64 + wh * 32 + (lhi << 3);
                const __half* bl0 = WtSl + tap * 2048 + l15 * 64 + wh * 32 + (lhi << 3);
#pragma unroll
                for (int nf = 0; nf < 2; ++nf) {
                    half8_t Bh = *(const half8_t*)(bh0 + nf * 1024);
                    half8_t Bl = *(const half8_t*)(bl0 + nf * 1024);
                    accA[nf] = __builtin_amdgcn_mfma_f32_16x16x32_f16(Ah, Bh, accA[nf], 0, 0, 0);
                    accA[nf] = __builtin_amdgcn_mfma_f32_16x16x32_f16(Ah, Bl, accA[nf], 0, 0, 0);
                    accA[nf] = __builtin_amdgcn_mfma_f32_16x16x32_f16(Al, Bh, accA[nf], 0, 0, 0);
                }
            }
        }

        // partial C -> LDS (summed at record time): Cred[w][pix16][ch(33)]
        float* Cred = (float*)arena;
#pragma unroll
        for (int nf = 0; nf < 2; ++nf)
#pragma unroll
            for (int v4 = 0; v4 < 4; ++v4)
                Cred[(w * 16 + (lhi << 2) + v4) * 33 + nf * 16 + l15] = accA[nf][v4];
    }
    __syncthreads();

    // ---------------- records: 32 pix x 9 n ----------------
    {
        const float* Cred = (const float*)arena;
#pragma unroll
        for (int j = 0; j < 2; ++j) {
            int rid = j * 256 + t;
            if (rid < 288) {
                int pb = rid & 31;
                int n = rid >> 5;
                int base0 = (((pb >> 4) * 2) * 16 + (pb & 15)) * 33;
                int base1 = base0 + 16 * 33;
                float sx = Cred[base0 + n] + Cred[base1 + n];
                float sy = Cred[base0 + 9 + n] + Cred[base1 + 9 + n];
                float sm = Cred[base0 + 18 + n] + Cred[base1 + 18 + n];

                int jj = col0 + pb;
                float px = ((sx + shift_b[n]) + (float)(n / 3 - 1)) + (float)(row + 1);
                float py = ((sy + shift_b[9 + n]) + (float)(n % 3 - 1)) + (float)(jj + 1);
                float mod = 1.f / (1.f + expf(-(sm + mod_b[n])));

                float fx = floorf(px), fy = floorf(py);
                int ltx = (int)fminf(fmaxf(fx, 0.f), 63.f);
                int lty = (int)fminf(fmaxf(fy, 0.f), 63.f);
                int rbx = (int)fminf(fmaxf(fx + 1.f, 0.f), 63.f);
                int rby = (int)fminf(fmaxf(fy + 1.f, 0.f), 63.f);
                int pxi = (int)fminf(fmaxf(px, 0.f), 63.f);
                int pyi = (int)fminf(fmaxf(py, 0.f), 63.f);

                int g_lt = (1 + ltx - pxi) * (1 + lty - pyi);
                int g_rb = (1 - rbx + pxi) * (1 - rby + pyi);
                int g_lb = (1 + ltx - pxi) * (1 + rby - pyi);
                int g_rt = (1 - rbx + pxi) * (1 - lty + pyi);

                int qxa[4] = {ltx, rbx, ltx, rbx};
                int qya[4] = {lty, rby, rby, lty};
                int gga[4] = {g_lt, g_rb, g_lb, g_rt};
                unsigned w0 = 0, w1 = 0;
#pragma unroll
                for (int jq = 0; jq < 4; ++jq) {
                    bool valid = (qxa[jq] >= 1) && (qya[jq] >= 1);
                    unsigned idx = valid ? (unsigned)((qxa[jq] - 1) * 64 + (qya[jq] - 1)) : 0u;
                    unsigned gc = valid ? (unsigned)gga[jq] : 0u;   // 0..2
                    if (jq < 2) w0 |= idx << (12 * jq); else w1 |= idx << (12 * (jq - 2));
                    w0 |= gc << (24 + 2 * jq);
                }
                recU[n][pb] = make_uint2(w0, w1);
                recF[n][pb] = mod;
            }
        }
    }
    __syncthreads();

    // ---------------- Phase B: main GEMM over 9 taps ----------------
    const __half* xbh = xTh + ((size_t)b << 18);
    int wm = w >> 1, wn = w & 1;
    int mA = t >> 3, cg = t & 7;     // A-build task: pixel mA, c-group cg

    f32x4 acc[4];
#pragma unroll
    for (int g = 0; g < 4; ++g) acc[g] = (f32x4){0.f, 0.f, 0.f, 0.f};

#pragma unroll
    for (int n = 0; n < 9; ++n) {
        // B fragments (L1-resident W): o = wn*64 + g*16 + l15, c = ks*32 + lhi*8
        const __half* Wn = WtH + n * 8192;
        uint4 Bv[2][4];
#pragma unroll
        for (int ks = 0; ks < 2; ++ks)
#pragma unroll
            for (int g = 0; g < 4; ++g)
                Bv[ks][g] = *(const uint4*)(Wn + ((wn * 64 + g * 16 + l15) << 6) +
                                            ks * 32 + (lhi << 3));

        // A build into slab[n&1]
        {
            uint2 rc = recU[n][mA];
            float mod = recF[n][mA];
            int id[4] = {(int)(rc.x & 0xFFF), (int)((rc.x >> 12) & 0xFFF),
                         (int)(rc.y & 0xFFF), (int)((rc.y >> 12) & 0xFFF)};
            __align__(16) __half2 a[4];
            a[0] = __half2(0, 0); a[1] = __half2(0, 0);
            a[2] = __half2(0, 0); a[3] = __half2(0, 0);
#pragma unroll
            for (int j = 0; j < 4; ++j) {
                float wf = (float)((rc.x >> (24 + 2 * j)) & 3) * mod;
                __half2 wh2 = __half2(__float2half_rn(wf), __float2half_rn(wf));
                uint4 v = *(const uint4*)(xbh + (id[j] << 6) + (cg << 3));
                const __half2* vv = (const __half2*)&v;
                a[0] = __hfma2(wh2, vv[0], a[0]);
                a[1] = __hfma2(wh2, vv[1], a[1]);
                a[2] = __hfma2(wh2, vv[2], a[2]);
                a[3] = __hfma2(wh2, vv[3], a[3]);
            }
            *(uint4*)&arena[((n & 1) << 12) | (mA << 7) | ((cg ^ (mA & 7)) << 4)] =
                *(uint4*)a;
        }
        __syncthreads();   // slab[n&1] complete (double-buffer -> 1 bar/n)

        // MFMA: A rows wm*16 + l15, k = ks*32 + lhi*8
#pragma unroll
        for (int ks = 0; ks < 2; ++ks) {
            int rowa = wm * 16 + l15;
            int gr = (ks * 4 + lhi) ^ (rowa & 7);
            half8_t Af = *(const half8_t*)&arena[((n & 1) << 12) | (rowa << 7) | (gr << 4)];
#pragma unroll
            for (int g = 0; g < 4; ++g) {
                half8_t Bf = *(half8_t*)&Bv[ks][g];
                acc[g] = __builtin_amdgcn_mfma_f32_16x16x32_f16(Af, Bf, acc[g], 0, 0, 0);
            }
        }
    }

    // ---------------- Epilogue: 4 rounds of 32 o-rows ----------------
    float* Ep = (float*)(arena + 8448);   // [32 o][33 m] scalar, conflict-free
    float* ob = out + ((size_t)b << 19);
    int prow = row * 64 + col0;
#pragma unroll
    for (int r = 0; r < 4; ++r) {
        if (wn == (r >> 1)) {
#pragma unroll
            for (int gg = 0; gg < 2; ++gg) {
                int g = (r & 1) * 2 + gg;
                int o_loc = gg * 16 + l15;
#pragma unroll
                for (int v4 = 0; v4 < 4; ++v4)
                    Ep[o_loc * 33 + wm * 16 + (lhi << 2) + v4] = acc[g][v4];
            }
        }
        __syncthreads();
        {
            int o_loc = t >> 3;          // 0..31
            int mseg = t & 7;            // 0..7
            float4 fa;
            fa.x = Ep[o_loc * 33 + mseg * 4 + 0];
            fa.y = Ep[o_loc * 33 + mseg * 4 + 1];
            fa.z = Ep[o_loc * 33 + mseg * 4 + 2];
            fa.w = Ep[o_loc * 33 + mseg * 4 + 3];
            float* dst = ob + ((size_t)(r * 32 + o_loc) << 12) + prow + mseg * 4;
            *(float4*)dst = fa;
        }
        __syncthreads();
    }
}

// ---------------------------------------------------------------------------
extern "C" void kernel_launch(void* const* d_in, const int* in_sizes, int n_in,
                              void* d_out, int out_size, void* d_ws, size_t ws_size,
                              hipStream_t stream) {
    const float* x = (const float*)d_in[0];
    const float* shift_w = (const float*)d_in[1];
    const float* shift_b = (const float*)d_in[2];
    const float* mod_w = (const float*)d_in[3];
    const float* mod_b = (const float*)d_in[4];
    const float* conv_w = (const float*)d_in[5];
    float* out = (float*)d_out;

    char* ws = (char*)d_ws;
    __half* xTh = (__half*)ws;                       // 4 MB
    __half* WtH = (__half*)(ws + 4194304);           // 144 KB
    __half* WtSh = (__half*)(ws + 4341760);          // 36 KB
    __half* WtSl = (__half*)(ws + 4378624);          // 36 KB  (total 4.41 MB)

    k_pre<<<dim3(872), dim3(256), 0, stream>>>(x, conv_w, shift_w, mod_w,
                                               xTh, WtH, WtSh, WtSl);
    k_fused<<<dim3(1024), dim3(256), 0, stream>>>(x, xTh, WtH, WtSh, WtSl,
                                                  shift_b, mod_b, out);
}